// Round 5
// baseline (129.921 us; speedup 1.0000x reference)
//
#include <hip/hip_runtime.h>
#include <math.h>

#define NN 1024
#define CC 91
#define MAXDET 100
typedef unsigned long long ull;
#define SENT 0xFFFFFFFFFFFFFFFFULL

struct alignas(16) D4 { double x, y, z, w; };

// ---------------- K1: softmax-max/argmax, decode, clip, key -------------------
__global__ __launch_bounds__(256) void k1_decode(
    const float* __restrict__ logits, const float* __restrict__ deltas,
    const float* __restrict__ props,  const int* __restrict__ imsz,
    D4* __restrict__ dbox, double* __restrict__ score64,
    int* __restrict__ label, ull* __restrict__ skeyG)
{
    int lane = threadIdx.x & 63;
    int wv   = threadIdx.x >> 6;
    int pid  = blockIdx.x * 4 + wv;            // 0..16383
    const float* lg = logits + (size_t)pid * CC;

    float v0 = lg[lane];
    float v1 = (lane < CC - 64) ? lg[64 + lane] : -INFINITY;
    float m; int idx;
    if (v0 >= v1) { m = v0; idx = lane; } else { m = v1; idx = 64 + lane; }
    #pragma unroll
    for (int off = 32; off > 0; off >>= 1) {
        float om = __shfl_xor(m, off);
        int   oi = __shfl_xor(idx, off);
        if (om > m || (om == m && oi < idx)) { m = om; idx = oi; }
    }
    double e = exp((double)v0 - (double)m);
    if (lane < CC - 64) e += exp((double)v1 - (double)m);
    #pragma unroll
    for (int off = 32; off > 0; off >>= 1) e += __shfl_xor(e, off);

    if (lane == 0) {
        double score = 1.0 / e;
        int lbl = idx;
        int vld = (lbl > 0 && score > 0.05) ? 1 : 0;
        float4 d = ((const float4*)deltas)[(size_t)pid * CC + lbl]; // 16B aligned
        float4 p = ((const float4*)props)[pid];
        double w  = (double)p.z - (double)p.x;
        double h  = (double)p.w - (double)p.y;
        double cx = (double)p.x + 0.5 * w;
        double cy = (double)p.y + 0.5 * h;
        const double CLIPV = 4.135166556742356;  // log(1000/16) in f64
        double dw = fmin((double)d.z, CLIPV), dh = fmin((double)d.w, CLIPV);
        double pcx = (double)d.x * w + cx, pcy = (double)d.y * h + cy;
        double pw = exp(dw) * w, ph = exp(dh) * h;
        double x1 = pcx - 0.5 * pw, y1 = pcy - 0.5 * ph;
        double x2 = pcx + 0.5 * pw, y2 = pcy + 0.5 * ph;
        int b = pid >> 10;
        double bw = (double)imsz[b * 2 + 1], bh = (double)imsz[b * 2 + 0];
        x1 = fmin(fmax(x1, 0.0), bw); y1 = fmin(fmax(y1, 0.0), bh);
        x2 = fmin(fmax(x2, 0.0), bw); y2 = fmin(fmax(y2, 0.0), bh);
        dbox[pid]    = D4{x1, y1, x2, y2};
        score64[pid] = score;
        label[pid]   = vld ? lbl : 0;          // 0 = skip in per-class NMS
        // sort key: descending score, ascending orig idx (stable argsort(-s))
        double seff = vld ? score : -1e300;
        ull u   = (ull)__double_as_longlong(seff);
        ull asc = (u >> 63) ? ~u : (u | 0x8000000000000000ULL);
        skeyG[pid] = (~asc & ~1023ULL) | (ull)(pid & 1023);
    }
}

// ---------------- K23: fused per-class NMS + top-100 (one block per image) ----
__global__ __launch_bounds__(1024) void k23_nms_top(
    const D4* __restrict__ dbox, const double* __restrict__ score64,
    const int* __restrict__ label, const ull* __restrict__ skeyG,
    float* __restrict__ out)
{
    __shared__ int sLbl[NN];          // 4 KB
    __shared__ ull sKey[NN];          // 8 KB
    __shared__ ull sKept[NN];         // 8 KB  kept key by position (SENT = not kept)
    __shared__ int sMemb[16 * 64];    // 4 KB
    __shared__ int sPosR[16 * 64];    // 4 KB
    __shared__ ull sKeyR[16 * 64];    // 8 KB
    int b = blockIdx.x, t = threadIdx.x;
    int lane = t & 63, wv = t >> 6;
    int base = b * NN;

    sLbl[t]  = label[base + t];
    sKey[t]  = skeyG[base + t];
    sKept[t] = SENT;
    __syncthreads();

    // ---- phase A: per-class greedy NMS, classes c = wv+1, wv+17, ... --------
    ull lmlt = (lane == 0) ? 0ULL : ((1ULL << lane) - 1ULL);
    for (int c = 1 + wv; c <= 90; c += 16) {
        // ballot-scan members of class c in position order (n>64 impossible)
        int nmem = 0;
        for (int w = 0; w < 16; ++w) {
            int p = w * 64 + lane;
            bool match = (sLbl[p] == c);
            ull mb = __ballot(match);
            if (match) {
                int slot = nmem + (int)__popcll(mb & lmlt);
                if (slot < 64) sMemb[wv * 64 + slot] = p;
            }
            nmem += (int)__popcll(mb);
            if (nmem >= 64) break;             // wave-uniform
        }
        int n = nmem < 64 ? nmem : 64;
        if (n == 0) continue;

        // rank members by key (score desc, idx asc)
        int p = sMemb[wv * 64 + (lane < n ? lane : 0)];
        ull key = sKey[p];
        int rank = 0;
        for (int j = 0; j < n; ++j) {
            ull kj = __shfl(key, j);
            rank += (int)(kj < key);
        }
        if (lane < n) { sPosR[wv * 64 + rank] = p; sKeyR[wv * 64 + rank] = key; }
        int rl  = wv * 64 + (lane < n ? lane : 0);
        int p2  = sPosR[rl];
        ull k2v = sKeyR[rl];

        D4 bx = dbox[base + p2];               // lane r holds rank-r box
        double ma = (bx.z - bx.x) * (bx.w - bx.y);
        ull pm = 0;                            // predecessor-hit mask (rank space)
        for (int j = 0; j < n; ++j) {
            double jx = __shfl(bx.x, j), jy = __shfl(bx.y, j);
            double jz = __shfl(bx.z, j), jw = __shfl(bx.w, j);
            double ja = __shfl(ma, j);
            double xx1 = fmax(bx.x, jx), yy1 = fmax(bx.y, jy);
            double xx2 = fmin(bx.z, jz), yy2 = fmin(bx.w, jw);
            double iw = fmax(xx2 - xx1, 0.0), ih = fmax(yy2 - yy1, 0.0);
            double inter = iw * ih;
            bool hit = (inter > 0.5 * (ma + ja - inter + 1e-9)) && (j < lane);
            pm |= ((ull)hit) << j;
        }
        bool act = lane < n;
        ull avail = __ballot(act);
        ull keptw = 0; bool supp = false;
        while (avail) {
            int k0 = __builtin_ctzll(avail);
            keptw |= 1ULL << k0;
            supp = supp || ((pm >> k0) & 1ULL);
            avail &= ~__ballot(supp);
            avail &= ~((2ULL << k0) - 1ULL);   // k0=63 -> 0
        }
        if (act && ((keptw >> lane) & 1ULL)) sKept[p2] = k2v;
    }
    __syncthreads();

    // ---- phase B: top-128 selection by key (bitonic partial merges) ---------
    ull key = sKept[t];
    for (int k = 2; k <= 64; k <<= 1)
        for (int j = k >> 1; j > 0; j >>= 1) {
            ull part = __shfl_xor(key, j);
            bool keepMin = ((lane & j) == 0) == ((lane & k) == 0);
            ull mn = key < part ? key : part;
            ull mx = key < part ? part : key;
            key = keepMin ? mn : mx;
        }
    __syncthreads();                           // sKept reads done before overwrite
    sKept[wv * 64 + lane] = key;
    __syncthreads();

    // L1: merge pairs of sorted-64 -> sorted-128 (waves 0..7)
    if (wv < 8) {
        ull a  = sKept[wv * 128 + lane];
        ull bb = sKept[wv * 128 + 64 + lane];
        ull br = __shfl(bb, 63 - lane);
        ull lo = a < br ? a : br;
        ull hi = a < br ? br : a;
        #pragma unroll
        for (int j = 32; j > 0; j >>= 1) {
            bool km = ((lane & j) == 0);
            ull pl = __shfl_xor(lo, j);
            lo = km ? (lo < pl ? lo : pl) : (lo < pl ? pl : lo);
            ull ph = __shfl_xor(hi, j);
            hi = km ? (hi < ph ? hi : ph) : (hi < ph ? ph : hi);
        }
        sKept[wv * 128 + lane] = lo;
        sKept[wv * 128 + 64 + lane] = hi;
    }
    // L2..L4: truncated merges of sorted-128 pairs -> smallest-128 sorted
    for (int nm = 4; nm >= 1; nm >>= 1) {
        __syncthreads();
        ull Alo = 0, Ahi = 0, Blo = 0, Bhi = 0;
        if (wv < nm) {
            Alo = sKept[wv * 256 + lane];
            Ahi = sKept[wv * 256 + 64 + lane];
            Blo = sKept[wv * 256 + 128 + lane];
            Bhi = sKept[wv * 256 + 192 + lane];
        }
        __syncthreads();
        if (wv < nm) {
            ull rBhi = __shfl(Bhi, 63 - lane);
            ull rBlo = __shfl(Blo, 63 - lane);
            ull Mlo = Alo < rBhi ? Alo : rBhi;   // min(A[i], B[127-i]) -> bitonic,
            ull Mhi = Ahi < rBlo ? Ahi : rBlo;   // contains the 128 smallest
            ull l2 = Mlo < Mhi ? Mlo : Mhi;      // clean stage j=64
            ull h2 = Mlo < Mhi ? Mhi : Mlo;
            #pragma unroll
            for (int j = 32; j > 0; j >>= 1) {
                bool km = ((lane & j) == 0);
                ull pl = __shfl_xor(l2, j);
                l2 = km ? (l2 < pl ? l2 : pl) : (l2 < pl ? pl : l2);
                ull ph = __shfl_xor(h2, j);
                h2 = km ? (h2 < ph ? h2 : ph) : (h2 < ph ? ph : h2);
            }
            sKept[wv * 128 + lane] = l2;
            sKept[wv * 128 + 64 + lane] = h2;
        }
    }
    // wave 0 wrote final sorted-128 to sKept[0..127]; same-wave read is ordered
    if (wv == 0) {
        float* oBox   = out;
        float* oScore = out + 6400;
        float* oLabel = out + 8000;
        #pragma unroll
        for (int rsel = 0; rsel < 2; ++rsel) {
            int rank = rsel * 64 + lane;
            if (rank < MAXDET) {
                ull kf = sKept[rsel * 64 + lane];
                int q = b * MAXDET + rank;
                if (kf == SENT) {
                    oBox[q * 4 + 0] = 0.f; oBox[q * 4 + 1] = 0.f;
                    oBox[q * 4 + 2] = 0.f; oBox[q * 4 + 3] = 0.f;
                    oScore[q] = 0.f;
                    oLabel[q] = -1.f;
                } else {
                    int p = (int)(kf & 1023ULL);
                    D4 bx = dbox[base + p];
                    oBox[q * 4 + 0] = (float)bx.x; oBox[q * 4 + 1] = (float)bx.y;
                    oBox[q * 4 + 2] = (float)bx.z; oBox[q * 4 + 3] = (float)bx.w;
                    oScore[q] = (float)score64[base + p];
                    oLabel[q] = (float)sLbl[p];
                }
            }
        }
    }
}

// ---------------- launch ------------------------------------------------------
extern "C" void kernel_launch(void* const* d_in, const int* in_sizes, int n_in,
                              void* d_out, int out_size, void* d_ws, size_t ws_size,
                              hipStream_t stream) {
    const float* logits = (const float*)d_in[0];
    const float* deltas = (const float*)d_in[1];
    const float* props  = (const float*)d_in[2];
    const int*   imsz   = (const int*)d_in[3];
    char* ws = (char*)d_ws;
    D4*     dbox    = (D4*)(ws + 0);             // 524288
    double* score64 = (double*)(ws + 524288);    // 131072
    int*    label   = (int*)(ws + 655360);       // 65536
    ull*    skeyG   = (ull*)(ws + 720896);       // 131072
    float* out = (float*)d_out;

    k1_decode<<<dim3(4096), dim3(256), 0, stream>>>(logits, deltas, props, imsz,
                                                    dbox, score64, label, skeyG);
    k23_nms_top<<<dim3(16), dim3(1024), 0, stream>>>(dbox, score64, label, skeyG, out);
}

// Round 6
// 102.983 us; speedup vs baseline: 1.2616x; 1.2616x over previous
//
#include <hip/hip_runtime.h>
#include <math.h>

#define NN 1024
#define CC 91
#define MAXDET 100
typedef unsigned long long ull;
#define SENT 0xFFFFFFFFFFFFFFFFULL

struct alignas(16) D4 { double x, y, z, w; };

// ---------------- K1: softmax-max/argmax, decode, clip, key, kept-init --------
__global__ __launch_bounds__(256) void k1_decode(
    const float* __restrict__ logits, const float* __restrict__ deltas,
    const float* __restrict__ props,  const int* __restrict__ imsz,
    D4* __restrict__ dbox, double* __restrict__ score64,
    int* __restrict__ label, ull* __restrict__ skeyG, ull* __restrict__ keptKey)
{
    int lane = threadIdx.x & 63;
    int wv   = threadIdx.x >> 6;
    int pid  = blockIdx.x * 4 + wv;            // 0..16383
    const float* lg = logits + (size_t)pid * CC;

    float v0 = lg[lane];
    float v1 = (lane < CC - 64) ? lg[64 + lane] : -INFINITY;
    float m; int idx;
    if (v0 >= v1) { m = v0; idx = lane; } else { m = v1; idx = 64 + lane; }
    #pragma unroll
    for (int off = 32; off > 0; off >>= 1) {
        float om = __shfl_xor(m, off);
        int   oi = __shfl_xor(idx, off);
        if (om > m || (om == m && oi < idx)) { m = om; idx = oi; }
    }
    double e = exp((double)v0 - (double)m);
    if (lane < CC - 64) e += exp((double)v1 - (double)m);
    #pragma unroll
    for (int off = 32; off > 0; off >>= 1) e += __shfl_xor(e, off);

    if (lane == 0) {
        double score = 1.0 / e;
        int lbl = idx;
        int vld = (lbl > 0 && score > 0.05) ? 1 : 0;
        float4 d = ((const float4*)deltas)[(size_t)pid * CC + lbl]; // 16B aligned
        float4 p = ((const float4*)props)[pid];
        double w  = (double)p.z - (double)p.x;
        double h  = (double)p.w - (double)p.y;
        double cx = (double)p.x + 0.5 * w;
        double cy = (double)p.y + 0.5 * h;
        const double CLIPV = 4.135166556742356;  // log(1000/16) in f64
        double dw = fmin((double)d.z, CLIPV), dh = fmin((double)d.w, CLIPV);
        double pcx = (double)d.x * w + cx, pcy = (double)d.y * h + cy;
        double pw = exp(dw) * w, ph = exp(dh) * h;
        double x1 = pcx - 0.5 * pw, y1 = pcy - 0.5 * ph;
        double x2 = pcx + 0.5 * pw, y2 = pcy + 0.5 * ph;
        int b = pid >> 10;
        double bw = (double)imsz[b * 2 + 1], bh = (double)imsz[b * 2 + 0];
        x1 = fmin(fmax(x1, 0.0), bw); y1 = fmin(fmax(y1, 0.0), bh);
        x2 = fmin(fmax(x2, 0.0), bw); y2 = fmin(fmax(y2, 0.0), bh);
        dbox[pid]    = D4{x1, y1, x2, y2};
        score64[pid] = score;
        label[pid]   = vld ? lbl : 0;          // 0 = skip in per-class NMS
        // sort key: descending score, ascending orig idx (stable argsort(-s))
        double seff = vld ? score : -1e300;
        ull u   = (ull)__double_as_longlong(seff);
        ull asc = (u >> 63) ? ~u : (u | 0x8000000000000000ULL);
        skeyG[pid]   = (~asc & ~1023ULL) | (ull)(pid & 1023);
        keptKey[pid] = SENT;
    }
}

// ---------------- K2: one wave per (image,class) greedy NMS -------------------
__global__ __launch_bounds__(256) void k2_nms(
    const D4* __restrict__ dbox, const int* __restrict__ label,
    const ull* __restrict__ skeyG, ull* __restrict__ keptKey)
{
    __shared__ int sMemb[4 * 64];
    __shared__ int sPosR[4 * 64];
    __shared__ ull sKeyR[4 * 64];
    int lane = threadIdx.x & 63, wv = threadIdx.x >> 6;
    int gw = blockIdx.x * 4 + wv;              // 0..1439
    int b  = gw / 90;
    int c  = 1 + gw % 90;                      // classes 1..90
    int base = b * NN;
    ull lmlt = (lane == 0) ? 0ULL : ((1ULL << lane) - 1ULL);

    // ballot-scan members of class c (position order; n>64 impossible, clamp)
    int nmem = 0;
    for (int w = 0; w < 16; ++w) {
        int p = w * 64 + lane;
        bool match = (label[base + p] == c);
        ull mb = __ballot(match);
        if (match) {
            int slot = nmem + (int)__popcll(mb & lmlt);
            if (slot < 64) sMemb[wv * 64 + slot] = p;
        }
        nmem += (int)__popcll(mb);
        if (nmem >= 64) break;                 // wave-uniform
    }
    int n = nmem < 64 ? nmem : 64;
    if (n == 0) return;                        // no __syncthreads in this kernel

    // rank members by key (score desc, idx asc)
    int p = sMemb[wv * 64 + (lane < n ? lane : 0)];
    ull key = skeyG[base + p];
    int rank = 0;
    for (int j = 0; j < n; ++j) {
        ull kj = __shfl(key, j);
        rank += (int)(kj < key);
    }
    if (lane < n) { sPosR[wv * 64 + rank] = p; sKeyR[wv * 64 + rank] = key; }
    // same-wave DS ops complete in order; compiler inserts lgkmcnt waits
    int rl  = wv * 64 + (lane < n ? lane : 0);
    int p2  = sPosR[rl];
    ull k2v = sKeyR[rl];

    D4 bx = dbox[base + p2];                   // lane r holds rank-r box
    double ma = (bx.z - bx.x) * (bx.w - bx.y);
    ull pm = 0;                                // predecessor-hit mask (rank space)
    for (int j = 0; j < n; ++j) {
        double jx = __shfl(bx.x, j), jy = __shfl(bx.y, j);
        double jz = __shfl(bx.z, j), jw = __shfl(bx.w, j);
        double ja = __shfl(ma, j);
        double xx1 = fmax(bx.x, jx), yy1 = fmax(bx.y, jy);
        double xx2 = fmin(bx.z, jz), yy2 = fmin(bx.w, jw);
        double iw = fmax(xx2 - xx1, 0.0), ih = fmax(yy2 - yy1, 0.0);
        double inter = iw * ih;
        bool hit = (inter > 0.5 * (ma + ja - inter + 1e-9)) && (j < lane);
        pm |= ((ull)hit) << j;
    }
    bool act = lane < n;
    ull avail = __ballot(act);
    ull keptw = 0; bool supp = false;
    while (avail) {
        int k0 = __builtin_ctzll(avail);
        keptw |= 1ULL << k0;
        supp = supp || ((pm >> k0) & 1ULL);
        avail &= ~__ballot(supp);
        avail &= ~((2ULL << k0) - 1ULL);       // k0=63 -> 0
    }
    if (act && ((keptw >> lane) & 1ULL)) keptKey[base + p2] = k2v;
}

// ---------------- K3: per-image top-100 by key via bitonic partial merges -----
__global__ __launch_bounds__(1024) void k3_top(
    const D4* __restrict__ dbox, const double* __restrict__ score64,
    const int* __restrict__ label, const ull* __restrict__ keptKey,
    float* __restrict__ out)
{
    __shared__ ull sRun[NN];
    int b = blockIdx.x, t = threadIdx.x;
    int lane = t & 63, wv = t >> 6;
    int base = b * NN;

    // in-wave 64-element bitonic sort, ascending (key asc == score desc)
    ull key = keptKey[base + t];
    for (int k = 2; k <= 64; k <<= 1)
        for (int j = k >> 1; j > 0; j >>= 1) {
            ull part = __shfl_xor(key, j);
            bool keepMin = ((lane & j) == 0) == ((lane & k) == 0);
            ull mn = key < part ? key : part;
            ull mx = key < part ? part : key;
            key = keepMin ? mn : mx;
        }
    sRun[wv * 64 + lane] = key;
    __syncthreads();

    // L1: merge pairs of sorted-64 -> sorted-128 (waves 0..7)
    if (wv < 8) {
        ull a  = sRun[wv * 128 + lane];
        ull bb = sRun[wv * 128 + 64 + lane];
        ull br = __shfl(bb, 63 - lane);
        ull lo = a < br ? a : br;
        ull hi = a < br ? br : a;
        #pragma unroll
        for (int j = 32; j > 0; j >>= 1) {
            bool km = ((lane & j) == 0);
            ull pl = __shfl_xor(lo, j);
            lo = km ? (lo < pl ? lo : pl) : (lo < pl ? pl : lo);
            ull ph = __shfl_xor(hi, j);
            hi = km ? (hi < ph ? hi : ph) : (hi < ph ? ph : hi);
        }
        sRun[wv * 128 + lane] = lo;
        sRun[wv * 128 + 64 + lane] = hi;
    }
    // L2..L4: truncated merges of sorted-128 pairs -> smallest-128 sorted
    for (int nm = 4; nm >= 1; nm >>= 1) {
        __syncthreads();
        ull Alo = 0, Ahi = 0, Blo = 0, Bhi = 0;
        if (wv < nm) {
            Alo = sRun[wv * 256 + lane];
            Ahi = sRun[wv * 256 + 64 + lane];
            Blo = sRun[wv * 256 + 128 + lane];
            Bhi = sRun[wv * 256 + 192 + lane];
        }
        __syncthreads();
        if (wv < nm) {
            ull rBhi = __shfl(Bhi, 63 - lane);
            ull rBlo = __shfl(Blo, 63 - lane);
            ull Mlo = Alo < rBhi ? Alo : rBhi;   // min(A[i], B[127-i]) -> bitonic,
            ull Mhi = Ahi < rBlo ? Ahi : rBlo;   // contains the 128 smallest
            ull l2 = Mlo < Mhi ? Mlo : Mhi;      // clean stage j=64
            ull h2 = Mlo < Mhi ? Mhi : Mlo;
            #pragma unroll
            for (int j = 32; j > 0; j >>= 1) {
                bool km = ((lane & j) == 0);
                ull pl = __shfl_xor(l2, j);
                l2 = km ? (l2 < pl ? l2 : pl) : (l2 < pl ? pl : l2);
                ull ph = __shfl_xor(h2, j);
                h2 = km ? (h2 < ph ? h2 : ph) : (h2 < ph ? ph : h2);
            }
            sRun[wv * 128 + lane] = l2;
            sRun[wv * 128 + 64 + lane] = h2;
        }
    }
    // wave 0 wrote final sorted-128 to sRun[0..127]; same-wave read is ordered
    if (wv == 0) {
        float* oBox   = out;
        float* oScore = out + 6400;
        float* oLabel = out + 8000;
        #pragma unroll
        for (int rsel = 0; rsel < 2; ++rsel) {
            int rank = rsel * 64 + lane;
            if (rank < MAXDET) {
                ull kf = sRun[rsel * 64 + lane];
                int q = b * MAXDET + rank;
                if (kf == SENT) {
                    oBox[q * 4 + 0] = 0.f; oBox[q * 4 + 1] = 0.f;
                    oBox[q * 4 + 2] = 0.f; oBox[q * 4 + 3] = 0.f;
                    oScore[q] = 0.f;
                    oLabel[q] = -1.f;
                } else {
                    int p = (int)(kf & 1023ULL);
                    D4 bx = dbox[base + p];
                    oBox[q * 4 + 0] = (float)bx.x; oBox[q * 4 + 1] = (float)bx.y;
                    oBox[q * 4 + 2] = (float)bx.z; oBox[q * 4 + 3] = (float)bx.w;
                    oScore[q] = (float)score64[base + p];
                    oLabel[q] = (float)label[base + p];
                }
            }
        }
    }
}

// ---------------- launch ------------------------------------------------------
extern "C" void kernel_launch(void* const* d_in, const int* in_sizes, int n_in,
                              void* d_out, int out_size, void* d_ws, size_t ws_size,
                              hipStream_t stream) {
    const float* logits = (const float*)d_in[0];
    const float* deltas = (const float*)d_in[1];
    const float* props  = (const float*)d_in[2];
    const int*   imsz   = (const int*)d_in[3];
    char* ws = (char*)d_ws;
    D4*     dbox    = (D4*)(ws + 0);             // 524288
    double* score64 = (double*)(ws + 524288);    // 131072
    int*    label   = (int*)(ws + 655360);       // 65536
    ull*    skeyG   = (ull*)(ws + 720896);       // 131072
    ull*    keptKey = (ull*)(ws + 851968);       // 131072
    float* out = (float*)d_out;

    k1_decode<<<dim3(4096), dim3(256), 0, stream>>>(logits, deltas, props, imsz,
                                                    dbox, score64, label, skeyG, keptKey);
    k2_nms<<<dim3(360), dim3(256), 0, stream>>>(dbox, label, skeyG, keptKey);
    k3_top<<<dim3(16), dim3(1024), 0, stream>>>(dbox, score64, label, keptKey, out);
}